// Round 1
// 537.303 us; speedup vs baseline: 1.0768x; 1.0768x over previous
//
#include <hip/hip_runtime.h>

#define NPIX (512*512)        // 262144 pixels per channel
#define N4   (NPIX/4)         // 65536 float4 per channel
#define DIM  128
#define HALF 64
#define CHW  ((size_t)DIM*NPIX)  // 33554432 elements per tensor

typedef float v4f __attribute__((ext_vector_type(4)));

__device__ __forceinline__ void nt_store4(const float4& v, float4* p) {
    v4f x; x.x = v.x; x.y = v.y; x.z = v.z; x.w = v.w;
    __builtin_nontemporal_store(x, (v4f*)p);
}

// ---------------- K1: per-channel means of lst and gui ----------------
__global__ __launch_bounds__(1024) void k_means(const float* __restrict__ lst,
                                                const float* __restrict__ gui,
                                                float* __restrict__ means) {
    int b = blockIdx.x;  // 0..127 = lst channels, 128..255 = gui channels
    const float* src = (b < DIM) ? (lst + (size_t)b * NPIX)
                                 : (gui + (size_t)(b - DIM) * NPIX);
    const float4* s4 = (const float4*)src;
    int t = threadIdx.x;
    float sum = 0.f;
#pragma unroll 8
    for (int k = 0; k < 64; ++k) {
        float4 v = s4[t + k * 1024];
        sum += (v.x + v.y) + (v.z + v.w);
    }
    for (int off = 32; off > 0; off >>= 1)
        sum += __shfl_down(sum, off, 64);
    __shared__ float red[16];
    int wave = t >> 6, lane = t & 63;
    if (lane == 0) red[wave] = sum;
    __syncthreads();
    if (t == 0) {
        float tot = 0.f;
        for (int w = 0; w < 16; ++w) tot += red[w];
        means[b] = tot * (1.0f / (float)NPIX);
    }
}

// ---------------- K2: MLPs + sigmoid + top-64 selection ----------------
__global__ __launch_bounds__(128) void k_select(
    const float* __restrict__ mask, const float* __restrict__ w1, const float* __restrict__ b1,
    const float* __restrict__ w2, const float* __restrict__ b2,
    const float* __restrict__ se_w1, const float* __restrict__ se_b1,
    const float* __restrict__ se_w2, const float* __restrict__ se_b2,
    const float* __restrict__ means,
    float* __restrict__ m_out, int* __restrict__ idx_out, int* __restrict__ uidx_out)
{
    int t = threadIdx.x;  // 0..127
    __shared__ float smask[64], h[128], pooled[256], se1[16], mv[128];
    __shared__ int sel[128];

    if (t < 64) smask[t] = mask[t];
    pooled[t]       = means[t];
    pooled[t + 128] = means[t + 128];
    __syncthreads();

    // h = relu(mask @ w1 + b1)   w1: [64,128] row-major
    float a = b1[t];
    for (int i = 0; i < 64; ++i) a = fmaf(smask[i], w1[i * DIM + t], a);
    h[t] = fmaxf(a, 0.f);
    __syncthreads();

    // mask1 = sigmoid(h @ w2 + b2)   w2: [128,128]
    float a2 = b2[t];
    for (int i = 0; i < 128; ++i) a2 = fmaf(h[i], w2[i * DIM + t], a2);
    float m1 = 1.f / (1.f + expf(-a2));

    // SE: se1 = relu(pooled @ se_w1 + se_b1)   se_w1: [256,16]
    if (t < 16) {
        float b = se_b1[t];
        for (int i = 0; i < 256; ++i) b = fmaf(pooled[i], se_w1[i * 16 + t], b);
        se1[t] = fmaxf(b, 0.f);
    }
    __syncthreads();

    // mask2 = sigmoid(se1 @ se_w2 + se_b2)   se_w2: [16,128]
    float a3 = se_b2[t];
    for (int i = 0; i < 16; ++i) a3 = fmaf(se1[i], se_w2[i * DIM + t], a3);
    float m2 = 1.f / (1.f + expf(-a3));

    float mval = m1 * m2;
    mv[t] = mval;
    m_out[t] = mval;
    __syncthreads();

    // stable top-64: rank = #(strictly greater) + #(equal with smaller index)
    int rank = 0;
    for (int i = 0; i < 128; ++i) {
        float o = mv[i];
        rank += (o > mval) || (o == mval && i < t);
    }
    int is_sel = (rank < HALF) ? 1 : 0;
    sel[t] = is_sel;
    __syncthreads();
    int pos = 0;
    for (int i = 0; i < t; ++i) pos += sel[i];
    if (is_sel) idx_out[pos] = t;          // ascending channel order
    else        uidx_out[t - pos] = t;     // ascending complement
}

// ---------------- K3: fused channel exchange + passthrough ----------------
// Each (blockIdx.x, z) block produces the full 128-channel output slab for
// its 64-float4 pixel window: conv for the 64 selected channels, register-
// staged copy for the 64 unselected ones. All stores nontemporal so the
// 268 MB of output writes don't evict the L3-resident inputs (just streamed
// by k_means) that this pass re-reads.
__device__ __forceinline__ void fma4(float4& a, float s, const float4& x) {
    a.x = fmaf(s, x.x, a.x);
    a.y = fmaf(s, x.y, a.y);
    a.z = fmaf(s, x.z, a.z);
    a.w = fmaf(s, x.w, a.w);
}

__global__ __launch_bounds__(256) void k_fused(
    const float* __restrict__ lst, const float* __restrict__ gui,
    const float* __restrict__ c1w, const float* __restrict__ c1b,
    const float* __restrict__ c2w, const float* __restrict__ c2b,
    const int* __restrict__ idx, const int* __restrict__ uidx,
    float* __restrict__ out)
{
    // z==0: out_lst <- conv2_w @ gui[idx] + conv2_b ; copy unselected lst
    // z==1: out_gui <- conv1_w @ lst[idx] + conv1_b ; copy unselected gui
    int z = blockIdx.y;
    const float* w    = (z == 0) ? c2w : c1w;
    const float* bias = (z == 0) ? c2b : c1b;
    const float4* conv_src = (const float4*)((z == 0) ? gui : lst);
    const float4* copy_src = (const float4*)((z == 0) ? lst : gui);
    float4* dst4 = (float4*)(out + (size_t)z * CHW);

    __shared__ float wT[HALF * HALF];   // wT[i*64 + o] = w[o*64 + i]
    __shared__ float bs[HALF];
    __shared__ int idxs[HALF];
    __shared__ int uidxs[HALF];
    int tid = threadIdx.x;
    for (int k = tid; k < HALF * HALF; k += 256) {
        int o = k >> 6, i = k & 63;
        wT[i * HALF + o] = w[k];
    }
    if (tid < HALF) { bs[tid] = bias[tid]; idxs[tid] = idx[tid]; uidxs[tid] = uidx[tid]; }
    __syncthreads();

    int tx = tid & 63;          // pixel group within block (coalescing dim)
    int ty = tid >> 6;          // 0..3 output-channel quarter
    int jbase = ty * 16;
    int p4 = blockIdx.x * 64 + tx;   // float4 index within a channel

    const float4* wT4 = (const float4*)wT;

    float4 acc[16];
#pragma unroll
    for (int j = 0; j < 16; ++j) {
        float b = bs[jbase + j];
        acc[j] = make_float4(b, b, b, b);
    }

#pragma unroll 2
    for (int i = 0; i < HALF; ++i) {
        int c = idxs[i];
        float4 x = conv_src[(size_t)c * N4 + p4];
#pragma unroll
        for (int q = 0; q < 4; ++q) {
            float4 w4 = wT4[i * 16 + ty * 4 + q];   // wave-uniform broadcast
            fma4(acc[q * 4 + 0], w4.x, x);
            fma4(acc[q * 4 + 1], w4.y, x);
            fma4(acc[q * 4 + 2], w4.z, x);
            fma4(acc[q * 4 + 3], w4.w, x);
        }
    }

    // conv results -> selected channels
#pragma unroll
    for (int j = 0; j < 16; ++j) {
        int c = idxs[jbase + j];
        nt_store4(acc[j], &dst4[(size_t)c * N4 + p4]);
    }

    // passthrough -> unselected channels (each wave owns 16 of the 64),
    // staged through registers in batches of 8 so loads overlap
#pragma unroll
    for (int r = 0; r < 2; ++r) {
        float4 v[8];
#pragma unroll
        for (int j = 0; j < 8; ++j)
            v[j] = copy_src[(size_t)uidxs[jbase + r * 8 + j] * N4 + p4];
#pragma unroll
        for (int j = 0; j < 8; ++j)
            nt_store4(v[j], &dst4[(size_t)uidxs[jbase + r * 8 + j] * N4 + p4]);
    }
}

extern "C" void kernel_launch(void* const* d_in, const int* in_sizes, int n_in,
                              void* d_out, int out_size, void* d_ws, size_t ws_size,
                              hipStream_t stream) {
    const float* lst   = (const float*)d_in[0];
    const float* gui   = (const float*)d_in[1];
    const float* mask  = (const float*)d_in[2];
    const float* w1    = (const float*)d_in[3];
    const float* b1    = (const float*)d_in[4];
    const float* w2    = (const float*)d_in[5];
    const float* b2    = (const float*)d_in[6];
    const float* se_w1 = (const float*)d_in[7];
    const float* se_b1 = (const float*)d_in[8];
    const float* se_w2 = (const float*)d_in[9];
    const float* se_b2 = (const float*)d_in[10];
    const float* c1w   = (const float*)d_in[11];
    const float* c1b   = (const float*)d_in[12];
    const float* c2w   = (const float*)d_in[13];
    const float* c2b   = (const float*)d_in[14];
    float* out = (float*)d_out;

    float* means = (float*)d_ws;                        // 256 floats
    int* idx     = (int*)((char*)d_ws + 1024);          // 64 ints
    int* uidx    = (int*)((char*)d_ws + 1024 + 256);    // 64 ints

    k_means<<<dim3(256), dim3(1024), 0, stream>>>(lst, gui, means);
    k_select<<<dim3(1), dim3(128), 0, stream>>>(mask, w1, b1, w2, b2,
                                                se_w1, se_b1, se_w2, se_b2,
                                                means, out + 2 * CHW, idx, uidx);
    k_fused<<<dim3(NPIX / 256, 2), dim3(256), 0, stream>>>(lst, gui, c1w, c1b, c2w, c2b,
                                                           idx, uidx, out);
}